// Round 1
// baseline (531.694 us; speedup 1.0000x reference)
//
#include <hip/hip_runtime.h>
#include <stdint.h>

#define N_NODES_C 50000
#define N_EDGES_C 1000000
#define NODE_DIM_C 128
#define EDGE_DIM_C 64

typedef __attribute__((ext_vector_type(8))) short short8;
typedef __attribute__((ext_vector_type(4))) float floatx4;

__device__ __forceinline__ short f2bf(float f) {
    union { float f; uint32_t u; } v; v.f = f;
    uint32_t u = v.u;
    uint32_t r = (u + 0x7FFFu + ((u >> 16) & 1u)) >> 16;  // RNE
    return (short)r;
}

__device__ __forceinline__ short8 pack8(float4 a0, float4 a1) {
    short8 o;
    o[0] = f2bf(a0.x); o[1] = f2bf(a0.y); o[2] = f2bf(a0.z); o[3] = f2bf(a0.w);
    o[4] = f2bf(a1.x); o[5] = f2bf(a1.y); o[6] = f2bf(a1.z); o[7] = f2bf(a1.w);
    return o;
}

__device__ __forceinline__ float gelu_tanh(float x) {
    // jax.nn.gelu approximate=True == x * sigmoid(2*sqrt(2/pi)*(x + 0.044715 x^3))
    float u = x * x;
    float inner = x * (1.0f + 0.044715f * u);
    float z = 1.5957691216057308f * inner;
    float ez = __expf(-z);
    return x / (1.0f + ez);
}

// ---------------- Kernel 1: node projections xs = x@Ws^T+bs, xt = x@Wt^T+bt ----
__global__ __launch_bounds__(256) void node_proj_kernel(
    const float* __restrict__ x,
    const float* __restrict__ Ws, const float* __restrict__ bs,
    const float* __restrict__ Wt, const float* __restrict__ bt,
    float* __restrict__ xs, float* __restrict__ xt)
{
    // B fragments for mfma_f32_16x16x32_bf16: B[k][n], n=lane&15, k=(lane>>4)*8+i
    __shared__ __align__(16) short ws_frag[4][4][64][8];  // [ntile][kstep][lane][i]
    __shared__ __align__(16) short wt_frag[4][4][64][8];

    const int tid = threadIdx.x;
    const int wave = tid >> 6, lane = tid & 63;
    const int m = lane & 15, q = lane >> 4;
    const int base = blockIdx.x * 64 + wave * 16;
    const int arow = base + m;

    // Prefetch this wave's x rows (issue before staging so latency overlaps)
    float4 av[4][2];
#pragma unroll
    for (int s = 0; s < 4; ++s) {
        if (arow < N_NODES_C) {
            const float4* ap = (const float4*)(x + arow * NODE_DIM_C + s * 32 + q * 8);
            av[s][0] = ap[0]; av[s][1] = ap[1];
        } else {
            av[s][0] = make_float4(0.f, 0.f, 0.f, 0.f);
            av[s][1] = make_float4(0.f, 0.f, 0.f, 0.f);
        }
    }

    // Stage weight fragments (vectorized float4 loads)
    for (int eidx = tid; eidx < 1024; eidx += 256) {
        int t = eidx >> 8;
        int s = (eidx >> 6) & 3;
        int l = eidx & 63;
        int n = t * 16 + (l & 15);
        int kb = s * 32 + ((l >> 4) << 3);
        const float4* wsr = (const float4*)(Ws + n * NODE_DIM_C + kb);
        const float4* wtr = (const float4*)(Wt + n * NODE_DIM_C + kb);
        float4 s0 = wsr[0], s1 = wsr[1];
        float4 t0 = wtr[0], t1 = wtr[1];
        *(short8*)ws_frag[t][s][l] = pack8(s0, s1);
        *(short8*)wt_frag[t][s][l] = pack8(t0, t1);
    }
    __syncthreads();

    floatx4 accS[4], accT[4];
    const floatx4 zero = {0.f, 0.f, 0.f, 0.f};
#pragma unroll
    for (int t = 0; t < 4; ++t) { accS[t] = zero; accT[t] = zero; }

#pragma unroll
    for (int s = 0; s < 4; ++s) {
        short8 a = pack8(av[s][0], av[s][1]);
#pragma unroll
        for (int t = 0; t < 4; ++t) {
            short8 bS = *(const short8*)ws_frag[t][s][lane];
            short8 bT = *(const short8*)wt_frag[t][s][lane];
            accS[t] = __builtin_amdgcn_mfma_f32_16x16x32_bf16(a, bS, accS[t], 0, 0, 0);
            accT[t] = __builtin_amdgcn_mfma_f32_16x16x32_bf16(a, bT, accT[t], 0, 0, 0);
        }
    }

#pragma unroll
    for (int t = 0; t < 4; ++t) {
        int col = t * 16 + m;
        float bsv = bs[col], btv = bt[col];
#pragma unroll
        for (int r = 0; r < 4; ++r) {
            int n = base + q * 4 + r;
            if (n < N_NODES_C) {
                xs[n * EDGE_DIM_C + col] = accS[t][r] + bsv;
                xt[n * EDGE_DIM_C + col] = accT[t][r] + btv;
            }
        }
    }
}

// ---------------- Kernel 2: fused edge MLP, one 64-edge chunk per block ---------
__global__ __launch_bounds__(256) void edge_mlp_kernel(
    const float* __restrict__ ea, const int* __restrict__ ei,
    const float* __restrict__ We, const float* __restrict__ be,
    const float* __restrict__ W1, const float* __restrict__ b1,
    const float* __restrict__ xs, const float* __restrict__ xt,
    float* __restrict__ out)
{
    __shared__ __align__(16) short we_frag[4][2][64][8];  // 8 KB
    __shared__ __align__(16) short w1_frag[4][2][64][8];  // 8 KB
    __shared__ __align__(16) short pbuf[4][16][72];       // per-wave gelu tile, padded

    const int tid = threadIdx.x;
    const int wave = tid >> 6, lane = tid & 63;
    const int m = lane & 15, q = lane >> 4;
    const int base = blockIdx.x * 64 + wave * 16;
    const int* __restrict__ src = ei;
    const int* __restrict__ tgt = ei + N_EDGES_C;

    // ---- 1. index loads FIRST (start of the dependent gather chain) ----
    int sidx[4], tidx[4];
#pragma unroll
    for (int r = 0; r < 4; ++r) {
        int e = base + q * 4 + r;
        int si = src[e], ti = tgt[e];
        sidx[r] = min(max(si, 0), N_NODES_C - 1);
        tidx[r] = min(max(ti, 0), N_NODES_C - 1);
    }

    // ---- 2. ea tile loads (independent) ----
    float4 av[4];
#pragma unroll
    for (int s = 0; s < 2; ++s) {
        const float4* ap = (const float4*)(ea + (base + m) * EDGE_DIM_C + s * 32 + q * 8);
        av[s * 2] = ap[0];
        av[s * 2 + 1] = ap[1];
    }

    // ---- 3. weight staging loads (independent; 2 fragment entries/thread) ----
    float4 web[2][2], w1b[2][2];
#pragma unroll
    for (int j = 0; j < 2; ++j) {
        int eidx = tid + j * 256;
        int t = eidx >> 7, s = (eidx >> 6) & 1, l = eidx & 63;
        int n = t * 16 + (l & 15);
        int kb = s * 32 + ((l >> 4) << 3);
        const float4* wer = (const float4*)(We + n * EDGE_DIM_C + kb);
        const float4* w1r = (const float4*)(W1 + n * EDGE_DIM_C + kb);
        web[j][0] = wer[0]; web[j][1] = wer[1];
        w1b[j][0] = w1r[0]; w1b[j][1] = w1r[1];
    }

    // bias vectors (tiny, L2-hot)
    float bev[4], b1v[4];
#pragma unroll
    for (int t = 0; t < 4; ++t) { bev[t] = be[t * 16 + m]; b1v[t] = b1[t * 16 + m]; }

    // ---- 4. gathers: issue as soon as indices land (only waits on step 1;
    //          ea/staging loads issued before stay in flight). Issued LAST so
    //          no later wait is forced to drain them. ----
    float gxs[4][4], gxt[4][4];  // [r][t]
#pragma unroll
    for (int r = 0; r < 4; ++r) {
        const float* ps = xs + (size_t)sidx[r] * EDGE_DIM_C + m;
        const float* pt = xt + (size_t)tidx[r] * EDGE_DIM_C + m;
#pragma unroll
        for (int t = 0; t < 4; ++t) {
            gxs[r][t] = ps[t * 16];
            gxt[r][t] = pt[t * 16];
        }
    }

    // ---- 5. stage weight fragments to LDS (waits staging loads, not gathers) ----
#pragma unroll
    for (int j = 0; j < 2; ++j) {
        int eidx = tid + j * 256;
        int t = eidx >> 7, s = (eidx >> 6) & 1, l = eidx & 63;
        *(short8*)we_frag[t][s][l] = pack8(web[j][0], web[j][1]);
        *(short8*)w1_frag[t][s][l] = pack8(w1b[j][0], w1b[j][1]);
    }

    // convert ea tile (waits only the ea loads)
    short8 af[2];
#pragma unroll
    for (int s = 0; s < 2; ++s) af[s] = pack8(av[s * 2], av[s * 2 + 1]);

    __syncthreads();

    // ---- GEMM1: e1 = ea @ We^T ----
    const floatx4 zero = {0.f, 0.f, 0.f, 0.f};
    floatx4 acc[4];
#pragma unroll
    for (int t = 0; t < 4; ++t) acc[t] = zero;
#pragma unroll
    for (int s = 0; s < 2; ++s) {
#pragma unroll
        for (int t = 0; t < 4; ++t) {
            short8 b = *(const short8*)we_frag[t][s][lane];
            acc[t] = __builtin_amdgcn_mfma_f32_16x16x32_bf16(af[s], b, acc[t], 0, 0, 0);
        }
    }

    // ---- epilogue 1: + be + xs[src] + xt[tgt], gelu, bf16 tile to LDS ----
#pragma unroll
    for (int t = 0; t < 4; ++t) {
#pragma unroll
        for (int r = 0; r < 4; ++r) {
            float c = acc[t][r] + bev[t] + gxs[r][t] + gxt[r][t];
            pbuf[wave][q * 4 + r][t * 16 + m] = f2bf(gelu_tanh(c));
        }
    }

    // ---- GEMM2: out = gelu_e @ W1^T (A from wave-private LDS) ----
    floatx4 acc2[4];
#pragma unroll
    for (int t = 0; t < 4; ++t) acc2[t] = zero;
#pragma unroll
    for (int s = 0; s < 2; ++s) {
        short8 a2 = *(const short8*)&pbuf[wave][m][s * 32 + q * 8];
#pragma unroll
        for (int t = 0; t < 4; ++t) {
            short8 b = *(const short8*)w1_frag[t][s][lane];
            acc2[t] = __builtin_amdgcn_mfma_f32_16x16x32_bf16(a2, b, acc2[t], 0, 0, 0);
        }
    }

    // ---- store (+ b1) ----
#pragma unroll
    for (int t = 0; t < 4; ++t) {
        int col = t * 16 + m;
#pragma unroll
        for (int r = 0; r < 4; ++r) {
            int e = base + q * 4 + r;
            out[e * EDGE_DIM_C + col] = acc2[t][r] + b1v[t];
        }
    }
}

extern "C" void kernel_launch(void* const* d_in, const int* in_sizes, int n_in,
                              void* d_out, int out_size, void* d_ws, size_t ws_size,
                              hipStream_t stream) {
    const float* x   = (const float*)d_in[0];
    const int*   ei  = (const int*)d_in[1];
    const float* ea  = (const float*)d_in[2];
    const float* We  = (const float*)d_in[3];
    const float* be  = (const float*)d_in[4];
    const float* Ws  = (const float*)d_in[5];
    const float* bs  = (const float*)d_in[6];
    const float* Wt  = (const float*)d_in[7];
    const float* bt  = (const float*)d_in[8];
    const float* W1  = (const float*)d_in[9];
    const float* b1  = (const float*)d_in[10];
    float* out = (float*)d_out;

    float* xs = (float*)d_ws;                        // 50000*64 fp32 = 12.8 MB
    float* xt = xs + (size_t)N_NODES_C * EDGE_DIM_C; // +12.8 MB

    dim3 blk(256);
    dim3 grid_nodes((N_NODES_C + 63) / 64);  // 782
    node_proj_kernel<<<grid_nodes, blk, 0, stream>>>(x, Ws, bs, Wt, bt, xs, xt);

    dim3 grid_edges(N_EDGES_C / 64);  // 15625 chunks, one per block
    edge_mlp_kernel<<<grid_edges, blk, 0, stream>>>(ea, ei, We, be, W1, b1, xs, xt, out);
}

// Round 2
// 508.160 us; speedup vs baseline: 1.0463x; 1.0463x over previous
//
#include <hip/hip_runtime.h>
#include <stdint.h>

#define N_NODES_C 50000
#define N_EDGES_C 1000000
#define NODE_DIM_C 128
#define EDGE_DIM_C 64

typedef __attribute__((ext_vector_type(8))) short short8;
typedef __attribute__((ext_vector_type(4))) float floatx4;

__device__ __forceinline__ short f2bf(float f) {
    union { float f; uint32_t u; } v; v.f = f;
    uint32_t u = v.u;
    uint32_t r = (u + 0x7FFFu + ((u >> 16) & 1u)) >> 16;  // RNE
    return (short)r;
}

__device__ __forceinline__ short8 pack8(float4 a0, float4 a1) {
    short8 o;
    o[0] = f2bf(a0.x); o[1] = f2bf(a0.y); o[2] = f2bf(a0.z); o[3] = f2bf(a0.w);
    o[4] = f2bf(a1.x); o[5] = f2bf(a1.y); o[6] = f2bf(a1.z); o[7] = f2bf(a1.w);
    return o;
}

__device__ __forceinline__ float f4get(const float4& v, int t) {
    return t == 0 ? v.x : t == 1 ? v.y : t == 2 ? v.z : v.w;
}

__device__ __forceinline__ float gelu_tanh(float x) {
    // jax.nn.gelu approximate=True == x * sigmoid(2*sqrt(2/pi)*(x + 0.044715 x^3))
    float u = x * x;
    float inner = x * (1.0f + 0.044715f * u);
    float z = 1.5957691216057308f * inner;
    float ez = __expf(-z);
    return x / (1.0f + ez);
}

// ---------------- Kernel 1: node projections (PERMUTED output layout) ----------
// xsp[n][m*4+t] = (x @ Ws^T + bs)[n][t*16+m]   (same for xtp/Wt/bt)
// This makes the edge kernel's per-lane gather a single contiguous float4.
__global__ __launch_bounds__(256) void node_proj_kernel(
    const float* __restrict__ x,
    const float* __restrict__ Ws, const float* __restrict__ bs,
    const float* __restrict__ Wt, const float* __restrict__ bt,
    float* __restrict__ xsp, float* __restrict__ xtp)
{
    __shared__ __align__(16) short ws_frag[4][4][64][8];  // [ntile][kstep][lane][i]
    __shared__ __align__(16) short wt_frag[4][4][64][8];

    const int tid = threadIdx.x;
    const int wave = tid >> 6, lane = tid & 63;
    const int m = lane & 15, q = lane >> 4;
    const int base = blockIdx.x * 64 + wave * 16;
    const int arow = base + m;

    // Prefetch this wave's x rows (issue before staging so latency overlaps)
    float4 av[4][2];
#pragma unroll
    for (int s = 0; s < 4; ++s) {
        if (arow < N_NODES_C) {
            const float4* ap = (const float4*)(x + arow * NODE_DIM_C + s * 32 + q * 8);
            av[s][0] = ap[0]; av[s][1] = ap[1];
        } else {
            av[s][0] = make_float4(0.f, 0.f, 0.f, 0.f);
            av[s][1] = make_float4(0.f, 0.f, 0.f, 0.f);
        }
    }

    // Stage weight fragments (vectorized float4 loads)
    for (int eidx = tid; eidx < 1024; eidx += 256) {
        int t = eidx >> 8;
        int s = (eidx >> 6) & 3;
        int l = eidx & 63;
        int n = t * 16 + (l & 15);
        int kb = s * 32 + ((l >> 4) << 3);
        const float4* wsr = (const float4*)(Ws + n * NODE_DIM_C + kb);
        const float4* wtr = (const float4*)(Wt + n * NODE_DIM_C + kb);
        float4 s0 = wsr[0], s1 = wsr[1];
        float4 t0 = wtr[0], t1 = wtr[1];
        *(short8*)ws_frag[t][s][l] = pack8(s0, s1);
        *(short8*)wt_frag[t][s][l] = pack8(t0, t1);
    }

    float bsv[4], btv[4];
#pragma unroll
    for (int t = 0; t < 4; ++t) { bsv[t] = bs[t * 16 + m]; btv[t] = bt[t * 16 + m]; }

    __syncthreads();

    floatx4 accS[4], accT[4];
    const floatx4 zero = {0.f, 0.f, 0.f, 0.f};
#pragma unroll
    for (int t = 0; t < 4; ++t) { accS[t] = zero; accT[t] = zero; }

#pragma unroll
    for (int s = 0; s < 4; ++s) {
        short8 a = pack8(av[s][0], av[s][1]);
#pragma unroll
        for (int t = 0; t < 4; ++t) {
            short8 bS = *(const short8*)ws_frag[t][s][lane];
            short8 bT = *(const short8*)wt_frag[t][s][lane];
            accS[t] = __builtin_amdgcn_mfma_f32_16x16x32_bf16(a, bS, accS[t], 0, 0, 0);
            accT[t] = __builtin_amdgcn_mfma_f32_16x16x32_bf16(a, bT, accT[t], 0, 0, 0);
        }
    }

    // Permuted store: lane (q,m) holds cols {m, 16+m, 32+m, 48+m} of row base+q*4+r
    // -> contiguous float4 at xsp[n*64 + m*4]
#pragma unroll
    for (int r = 0; r < 4; ++r) {
        int n = base + q * 4 + r;
        if (n < N_NODES_C) {
            float4 vs = make_float4(accS[0][r] + bsv[0], accS[1][r] + bsv[1],
                                    accS[2][r] + bsv[2], accS[3][r] + bsv[3]);
            float4 vt = make_float4(accT[0][r] + btv[0], accT[1][r] + btv[1],
                                    accT[2][r] + btv[2], accT[3][r] + btv[3]);
            *(float4*)(xsp + n * EDGE_DIM_C + m * 4) = vs;
            *(float4*)(xtp + n * EDGE_DIM_C + m * 4) = vt;
        }
    }
}

// ---------------- Kernel 2: fused edge MLP, 5 chunks/block, SW pipelined -------
__global__ __launch_bounds__(256) void edge_mlp_kernel(
    const float* __restrict__ ea, const int* __restrict__ ei,
    const float* __restrict__ We, const float* __restrict__ be,
    const float* __restrict__ W1, const float* __restrict__ b1,
    const float* __restrict__ xsp, const float* __restrict__ xtp,
    float* __restrict__ out)
{
    __shared__ __align__(16) short we_frag[4][2][64][8];  // 8 KB
    __shared__ __align__(16) short w1_frag[4][2][64][8];  // 8 KB
    __shared__ __align__(16) short pbuf[4][16][72];       // per-wave gelu tile

    const int tid = threadIdx.x;
    const int wave = tid >> 6, lane = tid & 63;
    const int m = lane & 15, q = lane >> 4;
    const int* __restrict__ src = ei;
    const int* __restrict__ tgt = ei + N_EDGES_C;

    const int G = 3125;                       // gridDim.x
    const int cstride = G * 64;               // edge stride between chunks
    const int cb0 = blockIdx.x * 64 + wave * 16;

    // ---------------- prolog (issue order matters for counted vmcnt) ----------
    // 1. idx[0]
    int4 sI[2], tI[2];
    sI[0] = *(const int4*)(src + cb0 + q * 4);
    tI[0] = *(const int4*)(tgt + cb0 + q * 4);

    // 2. ea[0]
    float4 eab[4];
    {
        const float4* ap = (const float4*)(ea + (cb0 + m) * EDGE_DIM_C);
        eab[0] = ap[q * 2];     eab[1] = ap[q * 2 + 1];
        eab[2] = ap[8 + q * 2]; eab[3] = ap[8 + q * 2 + 1];
    }

    // 3. weight staging loads
    float4 web[2][2], w1b[2][2];
#pragma unroll
    for (int j = 0; j < 2; ++j) {
        int eidx = tid + j * 256;
        int t = eidx >> 7, s = (eidx >> 6) & 1, l = eidx & 63;
        int n = t * 16 + (l & 15);
        int kb = s * 32 + ((l >> 4) << 3);
        const float4* wer = (const float4*)(We + n * EDGE_DIM_C + kb);
        const float4* w1r = (const float4*)(W1 + n * EDGE_DIM_C + kb);
        web[j][0] = wer[0]; web[j][1] = wer[1];
        w1b[j][0] = w1r[0]; w1b[j][1] = w1r[1];
    }

    // 4. idx[1]
    sI[1] = *(const int4*)(src + cb0 + cstride + q * 4);
    tI[1] = *(const int4*)(tgt + cb0 + cstride + q * 4);

    // 5. biases
    float bev[4], b1v[4];
#pragma unroll
    for (int t = 0; t < 4; ++t) { bev[t] = be[t * 16 + m]; b1v[t] = b1[t * 16 + m]; }

    // stage weights to LDS (waits staging loads only; idx[1]/bias stay in flight)
#pragma unroll
    for (int j = 0; j < 2; ++j) {
        int eidx = tid + j * 256;
        int t = eidx >> 7, s = (eidx >> 6) & 1, l = eidx & 63;
        *(short8*)we_frag[t][s][l] = pack8(web[j][0], web[j][1]);
        *(short8*)w1_frag[t][s][l] = pack8(w1b[j][0], w1b[j][1]);
    }
    __syncthreads();

    // issue gathers[0] (waits idx[0] only — oldest outstanding)
    float4 g_s[4], g_t[4];
    {
        int s0 = min(max(sI[0].x, 0), N_NODES_C - 1);
        int s1 = min(max(sI[0].y, 0), N_NODES_C - 1);
        int s2 = min(max(sI[0].z, 0), N_NODES_C - 1);
        int s3 = min(max(sI[0].w, 0), N_NODES_C - 1);
        int t0 = min(max(tI[0].x, 0), N_NODES_C - 1);
        int t1 = min(max(tI[0].y, 0), N_NODES_C - 1);
        int t2 = min(max(tI[0].z, 0), N_NODES_C - 1);
        int t3 = min(max(tI[0].w, 0), N_NODES_C - 1);
        g_s[0] = *(const float4*)(xsp + (s0 << 6) + m * 4);
        g_s[1] = *(const float4*)(xsp + (s1 << 6) + m * 4);
        g_s[2] = *(const float4*)(xsp + (s2 << 6) + m * 4);
        g_s[3] = *(const float4*)(xsp + (s3 << 6) + m * 4);
        g_t[0] = *(const float4*)(xtp + (t0 << 6) + m * 4);
        g_t[1] = *(const float4*)(xtp + (t1 << 6) + m * 4);
        g_t[2] = *(const float4*)(xtp + (t2 << 6) + m * 4);
        g_t[3] = *(const float4*)(xtp + (t3 << 6) + m * 4);
    }

    const floatx4 zero = {0.f, 0.f, 0.f, 0.f};

    // ---------------- pipelined main loop (fully unrolled: static buf indices) --
#pragma unroll
    for (int k = 0; k < 5; ++k) {
        // A: pack A-frag (waits ea[k]; counted vmcnt — gathers[k] etc stay out)
        short8 af0 = pack8(eab[0], eab[1]);
        short8 af1 = pack8(eab[2], eab[3]);

        // refill ea for chunk k+1
        if (k < 4) {
            const float4* ap = (const float4*)(ea + (cb0 + (k + 1) * cstride + m) * EDGE_DIM_C);
            eab[0] = ap[q * 2];     eab[1] = ap[q * 2 + 1];
            eab[2] = ap[8 + q * 2]; eab[3] = ap[8 + q * 2 + 1];
        }
        // prefetch idx for chunk k+2
        if (k < 3) {
            int b2 = cb0 + (k + 2) * cstride + q * 4;
            sI[k & 1] = *(const int4*)(src + b2);
            tI[k & 1] = *(const int4*)(tgt + b2);
        }

        // B: GEMM1
        floatx4 acc[4];
#pragma unroll
        for (int t = 0; t < 4; ++t) acc[t] = zero;
#pragma unroll
        for (int t = 0; t < 4; ++t) {
            short8 b = *(const short8*)we_frag[t][0][lane];
            acc[t] = __builtin_amdgcn_mfma_f32_16x16x32_bf16(af0, b, acc[t], 0, 0, 0);
        }
#pragma unroll
        for (int t = 0; t < 4; ++t) {
            short8 b = *(const short8*)we_frag[t][1][lane];
            acc[t] = __builtin_amdgcn_mfma_f32_16x16x32_bf16(af1, b, acc[t], 0, 0, 0);
        }

        // C: epilogue (waits gathers[k]; ea[k+1]/idx[k+2] stay in flight)
#pragma unroll
        for (int t = 0; t < 4; ++t) {
#pragma unroll
            for (int r = 0; r < 4; ++r) {
                float c = acc[t][r] + bev[t] + f4get(g_s[r], t) + f4get(g_t[r], t);
                pbuf[wave][q * 4 + r][t * 16 + m] = f2bf(gelu_tanh(c));
            }
        }

        // issue gathers for chunk k+1 (idx[k+1] landed ~1 iter ago)
        if (k < 4) {
            int4 s4 = sI[(k + 1) & 1], t4 = tI[(k + 1) & 1];
            int s0 = min(max(s4.x, 0), N_NODES_C - 1);
            int s1 = min(max(s4.y, 0), N_NODES_C - 1);
            int s2 = min(max(s4.z, 0), N_NODES_C - 1);
            int s3 = min(max(s4.w, 0), N_NODES_C - 1);
            int t0 = min(max(t4.x, 0), N_NODES_C - 1);
            int t1 = min(max(t4.y, 0), N_NODES_C - 1);
            int t2 = min(max(t4.z, 0), N_NODES_C - 1);
            int t3 = min(max(t4.w, 0), N_NODES_C - 1);
            g_s[0] = *(const float4*)(xsp + (s0 << 6) + m * 4);
            g_s[1] = *(const float4*)(xsp + (s1 << 6) + m * 4);
            g_s[2] = *(const float4*)(xsp + (s2 << 6) + m * 4);
            g_s[3] = *(const float4*)(xsp + (s3 << 6) + m * 4);
            g_t[0] = *(const float4*)(xtp + (t0 << 6) + m * 4);
            g_t[1] = *(const float4*)(xtp + (t1 << 6) + m * 4);
            g_t[2] = *(const float4*)(xtp + (t2 << 6) + m * 4);
            g_t[3] = *(const float4*)(xtp + (t3 << 6) + m * 4);
        }

        // D: GEMM2 (A from wave-private LDS tile; compiler inserts lgkm waits)
        floatx4 acc2[4];
#pragma unroll
        for (int t = 0; t < 4; ++t) acc2[t] = zero;
#pragma unroll
        for (int s = 0; s < 2; ++s) {
            short8 a2 = *(const short8*)&pbuf[wave][m][s * 32 + q * 8];
#pragma unroll
            for (int t = 0; t < 4; ++t) {
                short8 b = *(const short8*)w1_frag[t][s][lane];
                acc2[t] = __builtin_amdgcn_mfma_f32_16x16x32_bf16(a2, b, acc2[t], 0, 0, 0);
            }
        }

        // E: store (+ b1)
        const int ebase = cb0 + k * cstride;
#pragma unroll
        for (int t = 0; t < 4; ++t) {
            int col = t * 16 + m;
#pragma unroll
            for (int r = 0; r < 4; ++r) {
                int e = ebase + q * 4 + r;
                out[e * EDGE_DIM_C + col] = acc2[t][r] + b1v[t];
            }
        }
    }
}

extern "C" void kernel_launch(void* const* d_in, const int* in_sizes, int n_in,
                              void* d_out, int out_size, void* d_ws, size_t ws_size,
                              hipStream_t stream) {
    const float* x   = (const float*)d_in[0];
    const int*   ei  = (const int*)d_in[1];
    const float* ea  = (const float*)d_in[2];
    const float* We  = (const float*)d_in[3];
    const float* be  = (const float*)d_in[4];
    const float* Ws  = (const float*)d_in[5];
    const float* bs  = (const float*)d_in[6];
    const float* Wt  = (const float*)d_in[7];
    const float* bt  = (const float*)d_in[8];
    const float* W1  = (const float*)d_in[9];
    const float* b1  = (const float*)d_in[10];
    float* out = (float*)d_out;

    float* xsp = (float*)d_ws;                        // 50000*64 fp32 = 12.8 MB
    float* xtp = xsp + (size_t)N_NODES_C * EDGE_DIM_C; // +12.8 MB

    dim3 blk(256);
    dim3 grid_nodes((N_NODES_C + 63) / 64);  // 782
    node_proj_kernel<<<grid_nodes, blk, 0, stream>>>(x, Ws, bs, Wt, bt, xsp, xtp);

    dim3 grid_edges(3125);  // 15625 chunks of 64 edges, 5 per block (pipelined)
    edge_mlp_kernel<<<grid_edges, blk, 0, stream>>>(ea, ei, We, be, W1, b1, xsp, xtp, out);
}